// Round 1
// 6621.632 us; speedup vs baseline: 1.0060x; 1.0060x over previous
//
#include <hip/hip_runtime.h>

// Problem dims
#define HS_   1024
#define G4_   4096
#define EMB_  512
#define B_    64
#define S_    512
#define DIM_  128

typedef __attribute__((ext_vector_type(8))) short short8;
typedef __attribute__((ext_vector_type(4))) float floatx4;

__device__ __forceinline__ unsigned short f2bf(float f){
  union { float f; unsigned u; } v; v.f = f;
  unsigned r = v.u + 0x7FFFu + ((v.u >> 16) & 1u);   // RNE
  return (unsigned short)(r >> 16);
}
__device__ __forceinline__ float bf2f(unsigned short b){
  union { unsigned u; float f; } v; v.u = ((unsigned)b) << 16; return v.f;
}
// hi/lo split: f = bf2f(hi) + bf2f(lo) + O(f * 2^-18)
__device__ __forceinline__ void splitbf(float f, unsigned short& hi, unsigned short& lo){
  unsigned short h = f2bf(f);
  hi = h;
  lo = f2bf(f - bf2f(h));
}
__device__ __forceinline__ float sigm_f(float x){ return 1.0f/(1.0f + __expf(-x)); }
__device__ __forceinline__ float tanh_f(float x){ return 1.0f - 2.0f/(1.0f + __expf(2.0f*x)); }

// ---------------------------------------------------------------------------
// Kernel 1: x = event@Ve + 2*vc@Vc + 2*tanh(vn@Vn)  -> fp32 [32768][512]
// 128x128 tiles, split-bf16 3-pass 16x16x32 MFMA (~fp32 accuracy).
// ---------------------------------------------------------------------------
__global__ __launch_bounds__(256) void k_embed(
    const float* __restrict__ ev, const float* __restrict__ vcp, const float* __restrict__ vnp,
    const float* __restrict__ Ve, const float* __restrict__ Vc, const float* __restrict__ Vn,
    float* __restrict__ xout)
{
  __shared__ unsigned short a_hi[128][40], a_lo[128][40];
  __shared__ unsigned short b_hi[128][40], b_lo[128][40];   // transposed: [n][k]
  const int tid  = threadIdx.x;
  const int lane = tid & 63;
  const int w    = tid >> 6;
  const int wr = w >> 1, wc = w & 1;
  const int mt = blockIdx.x >> 2;
  const int nt = blockIdx.x & 3;
  const int m0 = mt * 128, n0 = nt * 128;
  const int fr = lane & 15;
  const int fk = (lane >> 4) * 8;

  floatx4 acc[4][4];
  #pragma unroll
  for (int i=0;i<4;i++)
    #pragma unroll
    for (int j=0;j<4;j++)
      acc[i][j] = (floatx4){0.f,0.f,0.f,0.f};

  auto do_stage = [&](const float* A, int lda, const float* Bm, int kBase, float bscale){
    __syncthreads();
    #pragma unroll
    for (int c=0;c<4;c++){
      int flat = tid*16 + c*4;
      int r = flat >> 5, kk = flat & 31;
      float4 v = *(const float4*)(A + (m0+r)*lda + kBase + kk);
      splitbf(v.x, a_hi[r][kk+0], a_lo[r][kk+0]);
      splitbf(v.y, a_hi[r][kk+1], a_lo[r][kk+1]);
      splitbf(v.z, a_hi[r][kk+2], a_lo[r][kk+2]);
      splitbf(v.w, a_hi[r][kk+3], a_lo[r][kk+3]);
    }
    #pragma unroll
    for (int c=0;c<4;c++){
      int flat = tid*16 + c*4;
      int k = flat >> 7, nn = flat & 127;
      float4 v = *(const float4*)(Bm + (kBase+k)*EMB_ + n0 + nn);
      splitbf(v.x * bscale, b_hi[nn+0][k], b_lo[nn+0][k]);
      splitbf(v.y * bscale, b_hi[nn+1][k], b_lo[nn+1][k]);
      splitbf(v.z * bscale, b_hi[nn+2][k], b_lo[nn+2][k]);
      splitbf(v.w * bscale, b_hi[nn+3][k], b_lo[nn+3][k]);
    }
    __syncthreads();
    short8 ah[4], al[4], bh[4], bl[4];
    #pragma unroll
    for (int mi=0;mi<4;mi++){
      ah[mi] = *(const short8*)&a_hi[wr*64 + mi*16 + fr][fk];
      al[mi] = *(const short8*)&a_lo[wr*64 + mi*16 + fr][fk];
    }
    #pragma unroll
    for (int ni=0;ni<4;ni++){
      bh[ni] = *(const short8*)&b_hi[wc*64 + ni*16 + fr][fk];
      bl[ni] = *(const short8*)&b_lo[wc*64 + ni*16 + fr][fk];
    }
    #pragma unroll
    for (int mi=0;mi<4;mi++)
      #pragma unroll
      for (int ni=0;ni<4;ni++){
        floatx4 t = acc[mi][ni];
        t = __builtin_amdgcn_mfma_f32_16x16x32_bf16(al[mi], bh[ni], t, 0, 0, 0);
        t = __builtin_amdgcn_mfma_f32_16x16x32_bf16(ah[mi], bl[ni], t, 0, 0, 0);
        t = __builtin_amdgcn_mfma_f32_16x16x32_bf16(ah[mi], bh[ni], t, 0, 0, 0);
        acc[mi][ni] = t;
      }
  };

  do_stage(vnp, 64, Vn, 0, 1.f);
  do_stage(vnp, 64, Vn, 32, 1.f);
  #pragma unroll
  for (int mi=0;mi<4;mi++)
    #pragma unroll
    for (int ni=0;ni<4;ni++)
      #pragma unroll
      for (int r=0;r<4;r++)
        acc[mi][ni][r] = 2.f * tanh_f(acc[mi][ni][r]);
  for (int ks=0; ks<32; ks++) do_stage(ev, 1024, Ve, ks*32, 1.f);
  for (int ks=0; ks<16; ks++) do_stage(vcp, 512, Vc, ks*32, 2.f);

  #pragma unroll
  for (int mi=0;mi<4;mi++)
    #pragma unroll
    for (int ni=0;ni<4;ni++){
      int col = n0 + wc*64 + ni*16 + fr;
      #pragma unroll
      for (int r=0;r<4;r++){
        int row = m0 + wr*64 + mi*16 + (lane>>4)*4 + r;
        xout[row*EMB_ + col] = acc[mi][ni][r];
      }
    }
}

// ---------------------------------------------------------------------------
// Kernel 2: xW = x@Wx + bias -> bf16, COLUMN-PERMUTED layout:
//   p = blk*16 + gate*4 + within,  source col n(p) = gate*1024 + blk*4 + within
// ---------------------------------------------------------------------------
__global__ __launch_bounds__(256) void k_xw(
    const float* __restrict__ x, const float* __restrict__ Wx,
    const float* __restrict__ bias, unsigned short* __restrict__ xwp)
{
  __shared__ unsigned short a_hi[128][40], a_lo[128][40];
  __shared__ unsigned short b_hi[128][40], b_lo[128][40];
  const int tid  = threadIdx.x;
  const int lane = tid & 63;
  const int w    = tid >> 6;
  const int wr = w >> 1, wc = w & 1;
  const int mt = blockIdx.x >> 5;
  const int nt = blockIdx.x & 31;
  const int m0 = mt * 128, p0 = nt * 128;
  const int fr = lane & 15;
  const int fk = (lane >> 4) * 8;

  floatx4 acc[4][4];
  #pragma unroll
  for (int i=0;i<4;i++)
    #pragma unroll
    for (int j=0;j<4;j++)
      acc[i][j] = (floatx4){0.f,0.f,0.f,0.f};

  for (int ks=0; ks<16; ks++){
    const int kBase = ks*32;
    __syncthreads();
    #pragma unroll
    for (int c=0;c<4;c++){
      int flat = tid*16 + c*4;
      int r = flat >> 5, kk = flat & 31;
      float4 v = *(const float4*)(x + (m0+r)*EMB_ + kBase + kk);
      splitbf(v.x, a_hi[r][kk+0], a_lo[r][kk+0]);
      splitbf(v.y, a_hi[r][kk+1], a_lo[r][kk+1]);
      splitbf(v.z, a_hi[r][kk+2], a_lo[r][kk+2]);
      splitbf(v.w, a_hi[r][kk+3], a_lo[r][kk+3]);
    }
    #pragma unroll
    for (int c=0;c<4;c++){
      int flat = tid*16 + c*4;
      int k = flat >> 7, pc = flat & 127;
      int p = p0 + pc;
      int nbase = ((p>>2)&3)*HS_ + (p>>4)*4;
      float4 v = *(const float4*)(Wx + (kBase+k)*G4_ + nbase);
      splitbf(v.x, b_hi[pc+0][k], b_lo[pc+0][k]);
      splitbf(v.y, b_hi[pc+1][k], b_lo[pc+1][k]);
      splitbf(v.z, b_hi[pc+2][k], b_lo[pc+2][k]);
      splitbf(v.w, b_hi[pc+3][k], b_lo[pc+3][k]);
    }
    __syncthreads();
    short8 ah[4], al[4], bh[4], bl[4];
    #pragma unroll
    for (int mi=0;mi<4;mi++){
      ah[mi] = *(const short8*)&a_hi[wr*64 + mi*16 + fr][fk];
      al[mi] = *(const short8*)&a_lo[wr*64 + mi*16 + fr][fk];
    }
    #pragma unroll
    for (int ni=0;ni<4;ni++){
      bh[ni] = *(const short8*)&b_hi[wc*64 + ni*16 + fr][fk];
      bl[ni] = *(const short8*)&b_lo[wc*64 + ni*16 + fr][fk];
    }
    #pragma unroll
    for (int mi=0;mi<4;mi++)
      #pragma unroll
      for (int ni=0;ni<4;ni++){
        floatx4 t = acc[mi][ni];
        t = __builtin_amdgcn_mfma_f32_16x16x32_bf16(al[mi], bh[ni], t, 0, 0, 0);
        t = __builtin_amdgcn_mfma_f32_16x16x32_bf16(ah[mi], bl[ni], t, 0, 0, 0);
        t = __builtin_amdgcn_mfma_f32_16x16x32_bf16(ah[mi], bh[ni], t, 0, 0, 0);
        acc[mi][ni] = t;
      }
  }

  #pragma unroll
  for (int ni=0;ni<4;ni++){
    int p = p0 + wc*64 + ni*16 + fr;
    int n = ((p>>2)&3)*HS_ + (p>>4)*4 + (p&3);
    float bv = bias[n];
    #pragma unroll
    for (int mi=0;mi<4;mi++){
      #pragma unroll
      for (int r=0;r<4;r++){
        int row = m0 + wr*64 + mi*16 + (lane>>4)*4 + r;
        xwp[row*G4_ + p] = f2bf(acc[mi][ni][r] + bv);
      }
    }
  }
}

// ---------------------------------------------------------------------------
// Kernel 3: persistent cooperative LSTM scan, 4 independent batch-groups.
// 256 blocks = 4 groups (16 batch rows each) x 64 col-blocks (64 gate-cols).
// NEW vs prev round:
//  - hbuf laid out as per-block contiguous tiles [grp][cb][16r][16c] bf16:
//    producer writes 4 full 128B lines (1 drain RT, no false sharing).
//  - group h (32 KB, contiguous) staged ONCE into LDS per step by all 256
//    threads (coalesced 16B chunks), XOR-swizzled; all 4 waves read MFMA
//    A-fragments from LDS -> 4x less L2/MALL read traffic per step.
//  - go word replicated 8x (128B apart); each block polls replica cb&7
//    -> 8 pollers per MALL line instead of 64.
// ---------------------------------------------------------------------------
__global__ __launch_bounds__(256, 1) void k_lstm(
    const unsigned short* __restrict__ xwp, unsigned short* __restrict__ hbuf,
    int* __restrict__ flags,
    const float* __restrict__ Wh, const float* __restrict__ Wc,
    const float* __restrict__ Wlin, const float* __restrict__ blin,
    float* __restrict__ out)
{
  __shared__ __align__(16) char hlds[32768];     // 64 tiles x 512 B, swizzled
  __shared__ float xw_lds[16][68];
  __shared__ float gbuf[16][68];
  __shared__ unsigned short hstage[16][16];
  __shared__ float red[256];
  const int tid  = threadIdx.x;
  const int lane = tid & 63;
  const int w    = tid >> 6;
  const int phys = blockIdx.x;
  const int grp  = (phys >> 3) & 3;              // batch group (8 blocks/XCD each)
  const int cb   = (phys & 7)*8 + (phys >> 5);   // col-block 0..63 (XCD-major)
  const int r0   = grp * 16;                     // first batch row
  const int p0   = cb * 64;                      // first permuted gate-col
  int* const arrive = flags + (grp*64 + cb)*16;            // arrive word
  int* const gorep  = flags + 4096 + (grp*8 + (cb&7))*32;  // this block's go replica

  // Pack Wh[:, 16 gate cols of this wave] into 32 register B-fragments.
  short8 wfrag[32];
  {
    const int p    = p0 + w*16 + (lane & 15);
    const int gcol = ((p>>2)&3)*HS_ + (p>>4)*4 + (p&3);
    const int kr0  = (lane >> 4) * 8;
    #pragma unroll
    for (int ks=0; ks<32; ks++){
      short8 v;
      #pragma unroll
      for (int j=0;j<8;j++)
        v[j] = (short)f2bf(Wh[(ks*32 + kr0 + j)*G4_ + gcol]);
      wfrag[ks] = v;
    }
  }

  // Elementwise assignment: thread -> (local row, local h-col), 1 element
  const int erow = tid >> 4, ej = tid & 15;
  const int hcol = cb*16 + ej;
  const float wc0 = Wc[hcol], wc1 = Wc[HS_ + hcol], wc2 = Wc[2*HS_ + hcol];
  const int gidx = (ej >> 2)*16 + (ej & 3);      // gate-0 index into 64-wide row
  float c_reg = 0.f;

  // A-fragment LDS base: tile = ks*2 + (lane>>5); row = lane&15; chunk=(lane>>4)&1
  // swizzle: slot = row*2 + (chunk ^ ((row>>2)&1))
  const int hrow  = lane & 15;
  const int hbase = (lane>>5)*512
                  + (hrow*2 + (((lane>>4)&1) ^ ((hrow>>2)&1)))*16;

  // xwp prefetch mapping: thread -> (row, 4-col chunk)
  const int prow = tid >> 4, pchunk = tid & 15;
  const unsigned short* xwbase = xwp + ((size_t)(r0 + prow)*S_)*G4_ + p0 + pchunk*4;

  // Prefetch step-0 xw chunk into registers
  ushort4 xwpre = *(const ushort4*)(xwbase);

  for (int t=0; t<S_; t++){
    const unsigned short* hin  = hbuf + (t & 1)*B_*HS_ + grp*16384;          // group tiles
    unsigned short*       hout = hbuf + ((t+1) & 1)*B_*HS_ + (grp*64+cb)*256; // own tile

    // Commit prefetched xw chunk to LDS
    xw_lds[prow][pchunk*4+0] = bf2f(xwpre.x);
    xw_lds[prow][pchunk*4+1] = bf2f(xwpre.y);
    xw_lds[prow][pchunk*4+2] = bf2f(xwpre.z);
    xw_lds[prow][pchunk*4+3] = bf2f(xwpre.w);

    // Stage group h (32 KB contiguous) -> LDS, coalesced 16B chunks, swizzled
    #pragma unroll
    for (int it=0; it<8; it++){
      int cid = it*256 + tid;                 // 16B-chunk id, 0..2047
      short8 v = *(const short8*)(hin + cid*8);
      int t2 = cid >> 5;                      // tile 0..63
      int rr = (cid >> 1) & 15;               // row
      int cc = cid & 1;                       // 8-col chunk
      *(short8*)(hlds + t2*512 + (rr*2 + (cc ^ ((rr>>2)&1)))*16) = v;
    }
    __syncthreads();

    // h @ Wh_slice : [16x1024]@[1024x16] per wave, A-fragments from LDS
    floatx4 a0 = (floatx4){0.f,0.f,0.f,0.f}, a1 = a0, a2 = a0, a3 = a0;
    #pragma unroll
    for (int ks=0; ks<32; ks+=4){
      short8 f0 = *(const short8*)(hlds + hbase + (ks+0)*1024);
      short8 f1 = *(const short8*)(hlds + hbase + (ks+1)*1024);
      short8 f2 = *(const short8*)(hlds + hbase + (ks+2)*1024);
      short8 f3 = *(const short8*)(hlds + hbase + (ks+3)*1024);
      a0 = __builtin_amdgcn_mfma_f32_16x16x32_bf16(f0, wfrag[ks+0], a0, 0,0,0);
      a1 = __builtin_amdgcn_mfma_f32_16x16x32_bf16(f1, wfrag[ks+1], a1, 0,0,0);
      a2 = __builtin_amdgcn_mfma_f32_16x16x32_bf16(f2, wfrag[ks+2], a2, 0,0,0);
      a3 = __builtin_amdgcn_mfma_f32_16x16x32_bf16(f3, wfrag[ks+3], a3, 0,0,0);
    }
    floatx4 acc = a0 + a1 + a2 + a3;

    // Scatter C to LDS: local col = w*16 + (lane&15), local row=(lane>>4)*4+r
    {
      const int gr = (lane>>4)*4;
      const int gc = w*16 + (lane & 15);
      gbuf[gr+0][gc] = acc[0];
      gbuf[gr+1][gc] = acc[1];
      gbuf[gr+2][gc] = acc[2];
      gbuf[gr+3][gc] = acc[3];
    }
    __syncthreads();

    // Elementwise LSTM cell (fp32 state in registers; peephole uses OLD c)
    {
      float gi = gbuf[erow][gidx     ] + xw_lds[erow][gidx     ];
      float gf = gbuf[erow][gidx +  4] + xw_lds[erow][gidx +  4];
      float gg = gbuf[erow][gidx +  8] + xw_lds[erow][gidx +  8];
      float go = gbuf[erow][gidx + 12] + xw_lds[erow][gidx + 12];
      float iv = sigm_f(gi + c_reg*wc0);
      float fv = sigm_f(gf + c_reg*wc1);
      float gv = tanh_f(gg);
      float ov = sigm_f(go + c_reg*wc2);
      float cn = fv*c_reg + iv*gv;
      float hn = ov*tanh_f(cn);
      c_reg = cn;
      hstage[erow][ej] = f2bf(hn);
    }
    __syncthreads();

    // Wave 0: pack + contiguous 8B sc1 stores (4 full lines, 1 drain RT)
    if (w == 0){
      unsigned long long hv = *(const unsigned long long*)&hstage[lane>>2][(lane&3)*4];
      __hip_atomic_store((unsigned long long*)(hout + lane*4),
                         hv, __ATOMIC_RELAXED, __HIP_MEMORY_SCOPE_AGENT);
      __builtin_amdgcn_s_waitcnt(0);             // h stores acked at coherence point
      if (lane == 0)
        __hip_atomic_store(arrive, t+1, __ATOMIC_RELAXED, __HIP_MEMORY_SCOPE_AGENT);
    }

    // Prefetch next step's xw chunk AFTER arrive-store (overlaps the go-wait)
    if (t+1 < S_) xwpre = *(const ushort4*)(xwbase + (size_t)(t+1)*G4_);

    // Leader (cb==0) wave 0: aggregate 64 arrive flags -> publish 8 go replicas.
    if (cb == 0 && w == 0){
      const int* fp = flags + (grp*64 + lane)*16;
      for (;;){
        int v = __hip_atomic_load(fp, __ATOMIC_RELAXED, __HIP_MEMORY_SCOPE_AGENT);
        if (__all(v >= t+1)) break;
        __builtin_amdgcn_s_sleep(2);
      }
      if (lane < 8)
        __hip_atomic_store(flags + 4096 + (grp*8 + lane)*32,
                           t+1, __ATOMIC_RELAXED, __HIP_MEMORY_SCOPE_AGENT);
    }
    // Everyone: single thread polls its group's go replica (8 pollers/line).
    if (tid == 0){
      for (;;){
        int v = __hip_atomic_load(gorep, __ATOMIC_RELAXED, __HIP_MEMORY_SCOPE_AGENT);
        if (v >= t+1) break;
        __builtin_amdgcn_s_sleep(2);
      }
    }
    __syncthreads();
    __builtin_amdgcn_fence(__ATOMIC_ACQUIRE, "agent");  // fresh h via coherence point
  }

  // Final: one (row, 32-col half) per block: out[row][ch*32+cl]
  // h element (r0+lr, k) lives at tile k>>4: hbuf[(grp*64 + (k>>4))*256 + lr*16 + (k&15)]
  {
    const int lr  = cb & 15;
    const int ch  = cb >> 4;
    const int cl = tid & 31, kc = tid >> 5;
    const int col = ch*32 + cl;
    const unsigned short* hg = hbuf + grp*16384;      // parity 0 after 512 steps
    float s = 0.f;
    for (int k = kc*128; k < kc*128 + 128; k++)
      s += bf2f(hg[(k>>4)*256 + lr*16 + (k&15)]) * Wlin[k*DIM_ + col];
    red[tid] = s;
    __syncthreads();
    if (tid < 32){
      float tot = blin[ch*32 + tid];
      #pragma unroll
      for (int q=0;q<8;q++) tot += red[q*32 + tid];
      out[(r0 + lr)*DIM_ + ch*32 + tid] = tot;
    }
  }
}

// ---------------------------------------------------------------------------
extern "C" void kernel_launch(void* const* d_in, const int* in_sizes, int n_in,
                              void* d_out, int out_size, void* d_ws, size_t ws_size,
                              hipStream_t stream)
{
  (void)in_sizes; (void)n_in; (void)out_size; (void)ws_size;
  const float* ev   = (const float*)d_in[0];
  const float* vcp  = (const float*)d_in[1];
  const float* vnp  = (const float*)d_in[2];
  const float* Ve   = (const float*)d_in[3];
  const float* Vc   = (const float*)d_in[4];
  const float* Vn   = (const float*)d_in[5];
  const float* Wx   = (const float*)d_in[6];
  const float* Wh   = (const float*)d_in[7];
  const float* Wc   = (const float*)d_in[8];
  const float* bias = (const float*)d_in[9];
  const float* Wl   = (const float*)d_in[10];
  const float* bl   = (const float*)d_in[11];
  float* outp = (float*)d_out;

  // ws layout: x fp32 (64MB) | xWP bf16 (256MB) | h double-buffer (256KB) | flags (32KB)
  char* ws = (char*)d_ws;
  float*          xf   = (float*)ws;
  unsigned short* xwp  = (unsigned short*)(ws + (size_t)67108864);
  unsigned short* hbuf = (unsigned short*)(ws + (size_t)67108864 + (size_t)268435456);
  int* flags           = (int*)(ws + (size_t)67108864 + (size_t)268435456 + (size_t)262144);

  // h0 = 0, arrive flags = 0, go replicas = 0
  hipMemsetAsync(hbuf, 0, 262144 + 32768, stream);

  k_embed<<<dim3(1024), dim3(256), 0, stream>>>(ev, vcp, vnp, Ve, Vc, Vn, xf);
  k_xw<<<dim3(8192), dim3(256), 0, stream>>>(xf, Wx, bias, xwp);

  const unsigned short* a0 = xwp;
  unsigned short* a1 = hbuf;
  int* a2 = flags;
  const float* a3 = Wh; const float* a4 = Wc;
  const float* a5 = Wl; const float* a6 = bl;
  float* a7 = outp;
  void* args[] = {&a0, &a1, &a2, &a3, &a4, &a5, &a6, &a7};
  hipLaunchCooperativeKernel((void*)k_lstm, dim3(256), dim3(256), args, 0, stream);
}

// Round 2
// 6203.343 us; speedup vs baseline: 1.0738x; 1.0674x over previous
//
#include <hip/hip_runtime.h>

// Problem dims
#define HS_   1024
#define G4_   4096
#define EMB_  512
#define B_    64
#define S_    512
#define DIM_  128

typedef __attribute__((ext_vector_type(8))) short short8;
typedef __attribute__((ext_vector_type(4))) float floatx4;

__device__ __forceinline__ unsigned short f2bf(float f){
  union { float f; unsigned u; } v; v.f = f;
  unsigned r = v.u + 0x7FFFu + ((v.u >> 16) & 1u);   // RNE
  return (unsigned short)(r >> 16);
}
__device__ __forceinline__ float bf2f(unsigned short b){
  union { unsigned u; float f; } v; v.u = ((unsigned)b) << 16; return v.f;
}
// hi/lo split: f = bf2f(hi) + bf2f(lo) + O(f * 2^-18)
__device__ __forceinline__ void splitbf(float f, unsigned short& hi, unsigned short& lo){
  unsigned short h = f2bf(f);
  hi = h;
  lo = f2bf(f - bf2f(h));
}
__device__ __forceinline__ float sigm_f(float x){ return 1.0f/(1.0f + __expf(-x)); }
__device__ __forceinline__ float tanh_f(float x){ return 1.0f - 2.0f/(1.0f + __expf(2.0f*x)); }

// ---------------------------------------------------------------------------
// Kernel 0: weight prep.
//  - Wx -> transposed, column-permuted split-bf16 planes wT[p][k] (p=permuted col)
//  - Wh -> bf16 fragments in the exact k_lstm per-(cb,wave) register layout
// ---------------------------------------------------------------------------
__global__ __launch_bounds__(256) void k_prep(
    const float* __restrict__ Wx, const float* __restrict__ Wh,
    unsigned short* __restrict__ wThi, unsigned short* __restrict__ wTlo,
    unsigned short* __restrict__ whf)
{
  const int id = blockIdx.x * 256 + threadIdx.x;
  if (blockIdx.x < 8192){                 // Wx part: 2M elems, id = p*512 + k
    const int p = id >> 9;
    const int k = id & 511;
    const int n = ((p>>2)&3)*HS_ + (p>>4)*4 + (p&3);
    unsigned short hi, lo;
    splitbf(Wx[k*G4_ + n], hi, lo);
    wThi[id] = hi;
    wTlo[id] = lo;
  } else {                                // Wh part: 4M elems
    const int f    = id - 2*1024*1024;
    const int j    = f & 7;
    const int lane = (f >> 3) & 63;
    const int ks   = (f >> 9) & 31;
    const int wv   = (f >> 14) & 3;
    const int cb   = f >> 16;
    const int p    = cb*64 + wv*16 + (lane & 15);
    const int gcol = ((p>>2)&3)*HS_ + (p>>4)*4 + (p&3);
    const int krow = ks*32 + (lane >> 4)*8 + j;
    whf[f] = f2bf(Wh[krow*G4_ + gcol]);
  }
}

// ---------------------------------------------------------------------------
// Kernel 1: x = event@Ve + 2*vc@Vc + 2*tanh(vn@Vn) -> split bf16 planes
// 128x128 tiles, split-bf16 3-pass 16x16x32 MFMA (~fp32 accuracy).
// ---------------------------------------------------------------------------
__global__ __launch_bounds__(256) void k_embed(
    const float* __restrict__ ev, const float* __restrict__ vcp, const float* __restrict__ vnp,
    const float* __restrict__ Ve, const float* __restrict__ Vc, const float* __restrict__ Vn,
    unsigned short* __restrict__ xhi, unsigned short* __restrict__ xlo)
{
  __shared__ unsigned short a_hi[128][40], a_lo[128][40];
  __shared__ unsigned short b_hi[128][40], b_lo[128][40];   // transposed: [n][k]
  const int tid  = threadIdx.x;
  const int lane = tid & 63;
  const int w    = tid >> 6;
  const int wr = w >> 1, wc = w & 1;
  const int mt = blockIdx.x >> 2;
  const int nt = blockIdx.x & 3;
  const int m0 = mt * 128, n0 = nt * 128;
  const int fr = lane & 15;
  const int fk = (lane >> 4) * 8;

  floatx4 acc[4][4];
  #pragma unroll
  for (int i=0;i<4;i++)
    #pragma unroll
    for (int j=0;j<4;j++)
      acc[i][j] = (floatx4){0.f,0.f,0.f,0.f};

  auto do_stage = [&](const float* A, int lda, const float* Bm, int kBase, float bscale){
    __syncthreads();
    #pragma unroll
    for (int c=0;c<4;c++){
      int flat = tid*16 + c*4;
      int r = flat >> 5, kk = flat & 31;
      float4 v = *(const float4*)(A + (m0+r)*lda + kBase + kk);
      splitbf(v.x, a_hi[r][kk+0], a_lo[r][kk+0]);
      splitbf(v.y, a_hi[r][kk+1], a_lo[r][kk+1]);
      splitbf(v.z, a_hi[r][kk+2], a_lo[r][kk+2]);
      splitbf(v.w, a_hi[r][kk+3], a_lo[r][kk+3]);
    }
    #pragma unroll
    for (int c=0;c<4;c++){
      int flat = tid*16 + c*4;
      int k = flat >> 7, nn = flat & 127;
      float4 v = *(const float4*)(Bm + (kBase+k)*EMB_ + n0 + nn);
      splitbf(v.x * bscale, b_hi[nn+0][k], b_lo[nn+0][k]);
      splitbf(v.y * bscale, b_hi[nn+1][k], b_lo[nn+1][k]);
      splitbf(v.z * bscale, b_hi[nn+2][k], b_lo[nn+2][k]);
      splitbf(v.w * bscale, b_hi[nn+3][k], b_lo[nn+3][k]);
    }
    __syncthreads();
    short8 ah[4], al[4], bh[4], bl[4];
    #pragma unroll
    for (int mi=0;mi<4;mi++){
      ah[mi] = *(const short8*)&a_hi[wr*64 + mi*16 + fr][fk];
      al[mi] = *(const short8*)&a_lo[wr*64 + mi*16 + fr][fk];
    }
    #pragma unroll
    for (int ni=0;ni<4;ni++){
      bh[ni] = *(const short8*)&b_hi[wc*64 + ni*16 + fr][fk];
      bl[ni] = *(const short8*)&b_lo[wc*64 + ni*16 + fr][fk];
    }
    #pragma unroll
    for (int mi=0;mi<4;mi++)
      #pragma unroll
      for (int ni=0;ni<4;ni++){
        floatx4 t = acc[mi][ni];
        t = __builtin_amdgcn_mfma_f32_16x16x32_bf16(al[mi], bh[ni], t, 0, 0, 0);
        t = __builtin_amdgcn_mfma_f32_16x16x32_bf16(ah[mi], bl[ni], t, 0, 0, 0);
        t = __builtin_amdgcn_mfma_f32_16x16x32_bf16(ah[mi], bh[ni], t, 0, 0, 0);
        acc[mi][ni] = t;
      }
  };

  do_stage(vnp, 64, Vn, 0, 1.f);
  do_stage(vnp, 64, Vn, 32, 1.f);
  #pragma unroll
  for (int mi=0;mi<4;mi++)
    #pragma unroll
    for (int ni=0;ni<4;ni++)
      #pragma unroll
      for (int r=0;r<4;r++)
        acc[mi][ni][r] = 2.f * tanh_f(acc[mi][ni][r]);
  for (int ks=0; ks<32; ks++) do_stage(ev, 1024, Ve, ks*32, 1.f);
  for (int ks=0; ks<16; ks++) do_stage(vcp, 512, Vc, ks*32, 2.f);

  #pragma unroll
  for (int mi=0;mi<4;mi++)
    #pragma unroll
    for (int ni=0;ni<4;ni++){
      int col = n0 + wc*64 + ni*16 + fr;
      #pragma unroll
      for (int r=0;r<4;r++){
        int row = m0 + wr*64 + mi*16 + (lane>>4)*4 + r;
        unsigned short hi, lo;
        splitbf(acc[mi][ni][r], hi, lo);
        xhi[row*EMB_ + col] = hi;
        xlo[row*EMB_ + col] = lo;
      }
    }
}

// ---------------------------------------------------------------------------
// Kernel 2: xW = x@Wx + bias -> bf16, column-permuted layout.
// Inputs are pre-split bf16 planes (x from k_embed, Wx transposed from k_prep)
// -> staging is pure 16B load + 16B ds_write, ZERO conversion VALU.
// Bijective XCD swizzle: each XCD owns 32 consecutive m-tiles (A-panel stays
// in its L2 across the 32 nt-tiles).
// ---------------------------------------------------------------------------
__global__ __launch_bounds__(256) void k_xw(
    const unsigned short* __restrict__ xhi, const unsigned short* __restrict__ xlo,
    const unsigned short* __restrict__ wThi, const unsigned short* __restrict__ wTlo,
    const float* __restrict__ bias, unsigned short* __restrict__ xwp)
{
  __shared__ unsigned short a_hi[128][40], a_lo[128][40];
  __shared__ unsigned short b_hi[128][40], b_lo[128][40];
  const int tid  = threadIdx.x;
  const int lane = tid & 63;
  const int w    = tid >> 6;
  const int wr = w >> 1, wc = w & 1;
  const int xcd = blockIdx.x & 7;
  const int xi  = blockIdx.x >> 3;
  const int mt = xcd*32 + (xi >> 5);
  const int nt = xi & 31;
  const int m0 = mt * 128, p0 = nt * 128;
  const int fr = lane & 15;
  const int fk = (lane >> 4) * 8;

  floatx4 acc[4][4];
  #pragma unroll
  for (int i=0;i<4;i++)
    #pragma unroll
    for (int j=0;j<4;j++)
      acc[i][j] = (floatx4){0.f,0.f,0.f,0.f};

  for (int ks=0; ks<16; ks++){
    const int kBase = ks*32;
    __syncthreads();
    #pragma unroll
    for (int c=0;c<2;c++){
      int ch = c*256 + tid;             // 0..511
      int r  = ch >> 2;                 // tile row / p-row
      int kk = (ch & 3)*8;              // k sub-chunk
      *(short8*)&a_hi[r][kk] = *(const short8*)(xhi  + (m0+r)*EMB_ + kBase + kk);
      *(short8*)&a_lo[r][kk] = *(const short8*)(xlo  + (m0+r)*EMB_ + kBase + kk);
      *(short8*)&b_hi[r][kk] = *(const short8*)(wThi + (p0+r)*EMB_ + kBase + kk);
      *(short8*)&b_lo[r][kk] = *(const short8*)(wTlo + (p0+r)*EMB_ + kBase + kk);
    }
    __syncthreads();
    short8 ah[4], al[4], bh[4], bl[4];
    #pragma unroll
    for (int mi=0;mi<4;mi++){
      ah[mi] = *(const short8*)&a_hi[wr*64 + mi*16 + fr][fk];
      al[mi] = *(const short8*)&a_lo[wr*64 + mi*16 + fr][fk];
    }
    #pragma unroll
    for (int ni=0;ni<4;ni++){
      bh[ni] = *(const short8*)&b_hi[wc*64 + ni*16 + fr][fk];
      bl[ni] = *(const short8*)&b_lo[wc*64 + ni*16 + fr][fk];
    }
    #pragma unroll
    for (int mi=0;mi<4;mi++)
      #pragma unroll
      for (int ni=0;ni<4;ni++){
        floatx4 t = acc[mi][ni];
        t = __builtin_amdgcn_mfma_f32_16x16x32_bf16(al[mi], bh[ni], t, 0, 0, 0);
        t = __builtin_amdgcn_mfma_f32_16x16x32_bf16(ah[mi], bl[ni], t, 0, 0, 0);
        t = __builtin_amdgcn_mfma_f32_16x16x32_bf16(ah[mi], bh[ni], t, 0, 0, 0);
        acc[mi][ni] = t;
      }
  }

  #pragma unroll
  for (int ni=0;ni<4;ni++){
    int p = p0 + wc*64 + ni*16 + fr;
    int n = ((p>>2)&3)*HS_ + (p>>4)*4 + (p&3);
    float bv = bias[n];
    #pragma unroll
    for (int mi=0;mi<4;mi++){
      #pragma unroll
      for (int r=0;r<4;r++){
        int row = m0 + wr*64 + mi*16 + (lane>>4)*4 + r;
        xwp[row*G4_ + p] = f2bf(acc[mi][ni][r] + bv);
      }
    }
  }
}

// ---------------------------------------------------------------------------
// Kernel 3: persistent cooperative LSTM scan, 4 independent batch-groups.
// 256 blocks = 4 groups (16 batch rows each) x 64 col-blocks (64 gate-cols).
//  - hbuf: per-block contiguous tiles [grp][cb][16r][16c] bf16 (full-line stores)
//  - group h staged once into LDS per step (coalesced, XOR-swizzled)
//  - go word replicated 8x; each block polls replica cb&7
//  - NEW: Wh fragments pre-packed by k_prep -> 32 coalesced 16B prologue loads
// ---------------------------------------------------------------------------
__global__ __launch_bounds__(256, 1) void k_lstm(
    const unsigned short* __restrict__ xwp, unsigned short* __restrict__ hbuf,
    int* __restrict__ flags, const unsigned short* __restrict__ whf,
    const float* __restrict__ Wc,
    const float* __restrict__ Wlin, const float* __restrict__ blin,
    float* __restrict__ out)
{
  __shared__ __align__(16) char hlds[32768];     // 64 tiles x 512 B, swizzled
  __shared__ float xw_lds[16][68];
  __shared__ float gbuf[16][68];
  __shared__ unsigned short hstage[16][16];
  __shared__ float red[256];
  const int tid  = threadIdx.x;
  const int lane = tid & 63;
  const int w    = tid >> 6;
  const int phys = blockIdx.x;
  const int grp  = (phys >> 3) & 3;              // batch group (8 blocks/XCD each)
  const int cb   = (phys & 7)*8 + (phys >> 5);   // col-block 0..63 (XCD-major)
  const int r0   = grp * 16;                     // first batch row
  const int p0   = cb * 64;                      // first permuted gate-col
  int* const arrive = flags + (grp*64 + cb)*16;            // arrive word
  int* const gorep  = flags + 4096 + (grp*8 + (cb&7))*32;  // this block's go replica

  // Wh B-fragments: pre-packed layout, 32 coalesced 16B loads.
  short8 wfrag[32];
  {
    const unsigned short* wbase = whf + ((size_t)(cb*4 + w))*16384 + lane*8;
    #pragma unroll
    for (int ks=0; ks<32; ks++)
      wfrag[ks] = *(const short8*)(wbase + ks*512);
  }

  // Elementwise assignment: thread -> (local row, local h-col), 1 element
  const int erow = tid >> 4, ej = tid & 15;
  const int hcol = cb*16 + ej;
  const float wc0 = Wc[hcol], wc1 = Wc[HS_ + hcol], wc2 = Wc[2*HS_ + hcol];
  const int gidx = (ej >> 2)*16 + (ej & 3);      // gate-0 index into 64-wide row
  float c_reg = 0.f;

  // A-fragment LDS base: tile = ks*2 + (lane>>5); row = lane&15; chunk=(lane>>4)&1
  // swizzle: slot = row*2 + (chunk ^ ((row>>2)&1))
  const int hrow  = lane & 15;
  const int hbase = (lane>>5)*512
                  + (hrow*2 + (((lane>>4)&1) ^ ((hrow>>2)&1)))*16;

  // xwp prefetch mapping: thread -> (row, 4-col chunk)
  const int prow = tid >> 4, pchunk = tid & 15;
  const unsigned short* xwbase = xwp + ((size_t)(r0 + prow)*S_)*G4_ + p0 + pchunk*4;

  // Prefetch step-0 xw chunk into registers
  ushort4 xwpre = *(const ushort4*)(xwbase);

  for (int t=0; t<S_; t++){
    const unsigned short* hin  = hbuf + (t & 1)*B_*HS_ + grp*16384;          // group tiles
    unsigned short*       hout = hbuf + ((t+1) & 1)*B_*HS_ + (grp*64+cb)*256; // own tile

    // Commit prefetched xw chunk to LDS
    xw_lds[prow][pchunk*4+0] = bf2f(xwpre.x);
    xw_lds[prow][pchunk*4+1] = bf2f(xwpre.y);
    xw_lds[prow][pchunk*4+2] = bf2f(xwpre.z);
    xw_lds[prow][pchunk*4+3] = bf2f(xwpre.w);

    // Stage group h (32 KB contiguous) -> LDS, coalesced 16B chunks, swizzled
    #pragma unroll
    for (int it=0; it<8; it++){
      int cid = it*256 + tid;                 // 16B-chunk id, 0..2047
      short8 v = *(const short8*)(hin + cid*8);
      int t2 = cid >> 5;                      // tile 0..63
      int rr = (cid >> 1) & 15;               // row
      int cc = cid & 1;                       // 8-col chunk
      *(short8*)(hlds + t2*512 + (rr*2 + (cc ^ ((rr>>2)&1)))*16) = v;
    }
    __syncthreads();

    // h @ Wh_slice : [16x1024]@[1024x16] per wave, A-fragments from LDS
    floatx4 a0 = (floatx4){0.f,0.f,0.f,0.f}, a1 = a0, a2 = a0, a3 = a0;
    #pragma unroll
    for (int ks=0; ks<32; ks+=4){
      short8 f0 = *(const short8*)(hlds + hbase + (ks+0)*1024);
      short8 f1 = *(const short8*)(hlds + hbase + (ks+1)*1024);
      short8 f2 = *(const short8*)(hlds + hbase + (ks+2)*1024);
      short8 f3 = *(const short8*)(hlds + hbase + (ks+3)*1024);
      a0 = __builtin_amdgcn_mfma_f32_16x16x32_bf16(f0, wfrag[ks+0], a0, 0,0,0);
      a1 = __builtin_amdgcn_mfma_f32_16x16x32_bf16(f1, wfrag[ks+1], a1, 0,0,0);
      a2 = __builtin_amdgcn_mfma_f32_16x16x32_bf16(f2, wfrag[ks+2], a2, 0,0,0);
      a3 = __builtin_amdgcn_mfma_f32_16x16x32_bf16(f3, wfrag[ks+3], a3, 0,0,0);
    }
    floatx4 acc = a0 + a1 + a2 + a3;

    // Scatter C to LDS: local col = w*16 + (lane&15), local row=(lane>>4)*4+r
    {
      const int gr = (lane>>4)*4;
      const int gc = w*16 + (lane & 15);
      gbuf[gr+0][gc] = acc[0];
      gbuf[gr+1][gc] = acc[1];
      gbuf[gr+2][gc] = acc[2];
      gbuf[gr+3][gc] = acc[3];
    }
    __syncthreads();

    // Elementwise LSTM cell (fp32 state in registers; peephole uses OLD c)
    {
      float gi = gbuf[erow][gidx     ] + xw_lds[erow][gidx     ];
      float gf = gbuf[erow][gidx +  4] + xw_lds[erow][gidx +  4];
      float gg = gbuf[erow][gidx +  8] + xw_lds[erow][gidx +  8];
      float go = gbuf[erow][gidx + 12] + xw_lds[erow][gidx + 12];
      float iv = sigm_f(gi + c_reg*wc0);
      float fv = sigm_f(gf + c_reg*wc1);
      float gv = tanh_f(gg);
      float ov = sigm_f(go + c_reg*wc2);
      float cn = fv*c_reg + iv*gv;
      float hn = ov*tanh_f(cn);
      c_reg = cn;
      hstage[erow][ej] = f2bf(hn);
    }
    __syncthreads();

    // Wave 0: pack + contiguous 8B sc1 stores (4 full lines, 1 drain RT)
    if (w == 0){
      unsigned long long hv = *(const unsigned long long*)&hstage[lane>>2][(lane&3)*4];
      __hip_atomic_store((unsigned long long*)(hout + lane*4),
                         hv, __ATOMIC_RELAXED, __HIP_MEMORY_SCOPE_AGENT);
      __builtin_amdgcn_s_waitcnt(0);             // h stores acked at coherence point
      if (lane == 0)
        __hip_atomic_store(arrive, t+1, __ATOMIC_RELAXED, __HIP_MEMORY_SCOPE_AGENT);
    }

    // Prefetch next step's xw chunk AFTER arrive-store (overlaps the go-wait)
    if (t+1 < S_) xwpre = *(const ushort4*)(xwbase + (size_t)(t+1)*G4_);

    // Leader (cb==0) wave 0: aggregate 64 arrive flags -> publish 8 go replicas.
    if (cb == 0 && w == 0){
      const int* fp = flags + (grp*64 + lane)*16;
      for (;;){
        int v = __hip_atomic_load(fp, __ATOMIC_RELAXED, __HIP_MEMORY_SCOPE_AGENT);
        if (__all(v >= t+1)) break;
        __builtin_amdgcn_s_sleep(2);
      }
      if (lane < 8)
        __hip_atomic_store(flags + 4096 + (grp*8 + lane)*32,
                           t+1, __ATOMIC_RELAXED, __HIP_MEMORY_SCOPE_AGENT);
    }
    // Everyone: single thread polls its group's go replica (8 pollers/line).
    if (tid == 0){
      for (;;){
        int v = __hip_atomic_load(gorep, __ATOMIC_RELAXED, __HIP_MEMORY_SCOPE_AGENT);
        if (v >= t+1) break;
        __builtin_amdgcn_s_sleep(2);
      }
    }
    __syncthreads();
    __builtin_amdgcn_fence(__ATOMIC_ACQUIRE, "agent");  // fresh h via coherence point
  }

  // Final: one (row, 32-col half) per block: out[row][ch*32+cl]
  // h element (r0+lr, k) lives at tile k>>4: hbuf[(grp*64 + (k>>4))*256 + lr*16 + (k&15)]
  {
    const int lr  = cb & 15;
    const int ch  = cb >> 4;
    const int cl = tid & 31, kc = tid >> 5;
    const int col = ch*32 + cl;
    const unsigned short* hg = hbuf + grp*16384;      // parity 0 after 512 steps
    float s = 0.f;
    for (int k = kc*128; k < kc*128 + 128; k++)
      s += bf2f(hg[(k>>4)*256 + lr*16 + (k&15)]) * Wlin[k*DIM_ + col];
    red[tid] = s;
    __syncthreads();
    if (tid < 32){
      float tot = blin[ch*32 + tid];
      #pragma unroll
      for (int q=0;q<8;q++) tot += red[q*32 + tid];
      out[(r0 + lr)*DIM_ + ch*32 + tid] = tot;
    }
  }
}

// ---------------------------------------------------------------------------
extern "C" void kernel_launch(void* const* d_in, const int* in_sizes, int n_in,
                              void* d_out, int out_size, void* d_ws, size_t ws_size,
                              hipStream_t stream)
{
  (void)in_sizes; (void)n_in; (void)out_size; (void)ws_size;
  const float* ev   = (const float*)d_in[0];
  const float* vcp  = (const float*)d_in[1];
  const float* vnp  = (const float*)d_in[2];
  const float* Ve   = (const float*)d_in[3];
  const float* Vc   = (const float*)d_in[4];
  const float* Vn   = (const float*)d_in[5];
  const float* Wx   = (const float*)d_in[6];
  const float* Wh   = (const float*)d_in[7];
  const float* Wc   = (const float*)d_in[8];
  const float* bias = (const float*)d_in[9];
  const float* Wl   = (const float*)d_in[10];
  const float* bl   = (const float*)d_in[11];
  float* outp = (float*)d_out;

  // ws layout (bytes):
  //   xhi  32MB @ 0         | xlo 32MB @ 32MB
  //   wThi  4MB @ 64MB      | wTlo 4MB @ 68MB
  //   whf   8MB @ 72MB
  //   xwp 256MB @ 80MB
  //   hbuf 256KB @ 336MB    | flags 32KB after
  char* ws = (char*)d_ws;
  unsigned short* xhi  = (unsigned short*)(ws);
  unsigned short* xlo  = (unsigned short*)(ws + (size_t)33554432);
  unsigned short* wThi = (unsigned short*)(ws + (size_t)67108864);
  unsigned short* wTlo = (unsigned short*)(ws + (size_t)71303168);
  unsigned short* whf  = (unsigned short*)(ws + (size_t)75497472);
  unsigned short* xwp  = (unsigned short*)(ws + (size_t)83886080);
  unsigned short* hbuf = (unsigned short*)(ws + (size_t)352321536);
  int* flags           = (int*)(ws + (size_t)352321536 + (size_t)262144);

  // h0 = 0, arrive flags = 0, go replicas = 0
  hipMemsetAsync(hbuf, 0, 262144 + 32768, stream);

  k_prep <<<dim3(24576), dim3(256), 0, stream>>>(Wx, Wh, wThi, wTlo, whf);
  k_embed<<<dim3(1024),  dim3(256), 0, stream>>>(ev, vcp, vnp, Ve, Vc, Vn, xhi, xlo);
  k_xw   <<<dim3(8192),  dim3(256), 0, stream>>>(xhi, xlo, wThi, wTlo, bias, xwp);

  const unsigned short* a0 = xwp;
  unsigned short* a1 = hbuf;
  int* a2 = flags;
  const unsigned short* a3 = whf;
  const float* a4 = Wc;
  const float* a5 = Wl; const float* a6 = bl;
  float* a7 = outp;
  void* args[] = {&a0, &a1, &a2, &a3, &a4, &a5, &a6, &a7};
  hipLaunchCooperativeKernel((void*)k_lstm, dim3(256), dim3(256), args, 0, stream);
}

// Round 3
// 5314.951 us; speedup vs baseline: 1.2533x; 1.1671x over previous
//
#include <hip/hip_runtime.h>

// Problem dims
#define HS_   1024
#define G4_   4096
#define EMB_  512
#define B_    64
#define S_    512
#define DIM_  128

typedef __attribute__((ext_vector_type(8))) short short8;
typedef __attribute__((ext_vector_type(4))) float floatx4;

__device__ __forceinline__ unsigned short f2bf(float f){
  union { float f; unsigned u; } v; v.f = f;
  unsigned r = v.u + 0x7FFFu + ((v.u >> 16) & 1u);   // RNE
  return (unsigned short)(r >> 16);
}
__device__ __forceinline__ float bf2f(unsigned short b){
  union { unsigned u; float f; } v; v.u = ((unsigned)b) << 16; return v.f;
}
// hi/lo split: f = bf2f(hi) + bf2f(lo) + O(f * 2^-18)
__device__ __forceinline__ void splitbf(float f, unsigned short& hi, unsigned short& lo){
  unsigned short h = f2bf(f);
  hi = h;
  lo = f2bf(f - bf2f(h));
}
__device__ __forceinline__ float sigm_f(float x){ return 1.0f/(1.0f + __expf(-x)); }
__device__ __forceinline__ float tanh_f(float x){ return 1.0f - 2.0f/(1.0f + __expf(2.0f*x)); }

// ---------------------------------------------------------------------------
// Kernel 0: weight prep.
//  - Wx -> transposed, column-permuted split-bf16 planes wT[p][k]
//  - Wh -> bf16 fragments in the exact k_lstm per-(cb,wave) register layout
//    (NEW layout: cb 0..31 x wv 0..7)
// ---------------------------------------------------------------------------
__global__ __launch_bounds__(256) void k_prep(
    const float* __restrict__ Wx, const float* __restrict__ Wh,
    unsigned short* __restrict__ wThi, unsigned short* __restrict__ wTlo,
    unsigned short* __restrict__ whf)
{
  const int id = blockIdx.x * 256 + threadIdx.x;
  if (blockIdx.x < 8192){                 // Wx part: 2M elems, id = p*512 + k
    const int p = id >> 9;
    const int k = id & 511;
    const int n = ((p>>2)&3)*HS_ + (p>>4)*4 + (p&3);
    unsigned short hi, lo;
    splitbf(Wx[k*G4_ + n], hi, lo);
    wThi[id] = hi;
    wTlo[id] = lo;
  } else {                                // Wh part: 4M elems
    const int f    = id - 2*1024*1024;
    const int j    = f & 7;
    const int lane = (f >> 3) & 63;
    const int ks   = (f >> 9) & 31;
    const int wv   = (f >> 14) & 7;
    const int cb   = f >> 17;             // 0..31
    const int p    = cb*128 + wv*16 + (lane & 15);
    const int gcol = ((p>>2)&3)*HS_ + (p>>4)*4 + (p&3);
    const int krow = ks*32 + (lane >> 4)*8 + j;
    whf[f] = f2bf(Wh[krow*G4_ + gcol]);
  }
}

// ---------------------------------------------------------------------------
// Kernel 1: x = event@Ve + 2*vc@Vc + 2*tanh(vn@Vn) -> split bf16 planes
// 128x128 tiles, split-bf16 3-pass 16x16x32 MFMA (~fp32 accuracy).
// ---------------------------------------------------------------------------
__global__ __launch_bounds__(256) void k_embed(
    const float* __restrict__ ev, const float* __restrict__ vcp, const float* __restrict__ vnp,
    const float* __restrict__ Ve, const float* __restrict__ Vc, const float* __restrict__ Vn,
    unsigned short* __restrict__ xhi, unsigned short* __restrict__ xlo)
{
  __shared__ unsigned short a_hi[128][40], a_lo[128][40];
  __shared__ unsigned short b_hi[128][40], b_lo[128][40];   // transposed: [n][k]
  const int tid  = threadIdx.x;
  const int lane = tid & 63;
  const int w    = tid >> 6;
  const int wr = w >> 1, wc = w & 1;
  const int mt = blockIdx.x >> 2;
  const int nt = blockIdx.x & 3;
  const int m0 = mt * 128, n0 = nt * 128;
  const int fr = lane & 15;
  const int fk = (lane >> 4) * 8;

  floatx4 acc[4][4];
  #pragma unroll
  for (int i=0;i<4;i++)
    #pragma unroll
    for (int j=0;j<4;j++)
      acc[i][j] = (floatx4){0.f,0.f,0.f,0.f};

  auto do_stage = [&](const float* A, int lda, const float* Bm, int kBase, float bscale){
    __syncthreads();
    #pragma unroll
    for (int c=0;c<4;c++){
      int flat = tid*16 + c*4;
      int r = flat >> 5, kk = flat & 31;
      float4 v = *(const float4*)(A + (m0+r)*lda + kBase + kk);
      splitbf(v.x, a_hi[r][kk+0], a_lo[r][kk+0]);
      splitbf(v.y, a_hi[r][kk+1], a_lo[r][kk+1]);
      splitbf(v.z, a_hi[r][kk+2], a_lo[r][kk+2]);
      splitbf(v.w, a_hi[r][kk+3], a_lo[r][kk+3]);
    }
    #pragma unroll
    for (int c=0;c<4;c++){
      int flat = tid*16 + c*4;
      int k = flat >> 7, nn = flat & 127;
      float4 v = *(const float4*)(Bm + (kBase+k)*EMB_ + n0 + nn);
      splitbf(v.x * bscale, b_hi[nn+0][k], b_lo[nn+0][k]);
      splitbf(v.y * bscale, b_hi[nn+1][k], b_lo[nn+1][k]);
      splitbf(v.z * bscale, b_hi[nn+2][k], b_lo[nn+2][k]);
      splitbf(v.w * bscale, b_hi[nn+3][k], b_lo[nn+3][k]);
    }
    __syncthreads();
    short8 ah[4], al[4], bh[4], bl[4];
    #pragma unroll
    for (int mi=0;mi<4;mi++){
      ah[mi] = *(const short8*)&a_hi[wr*64 + mi*16 + fr][fk];
      al[mi] = *(const short8*)&a_lo[wr*64 + mi*16 + fr][fk];
    }
    #pragma unroll
    for (int ni=0;ni<4;ni++){
      bh[ni] = *(const short8*)&b_hi[wc*64 + ni*16 + fr][fk];
      bl[ni] = *(const short8*)&b_lo[wc*64 + ni*16 + fr][fk];
    }
    #pragma unroll
    for (int mi=0;mi<4;mi++)
      #pragma unroll
      for (int ni=0;ni<4;ni++){
        floatx4 t = acc[mi][ni];
        t = __builtin_amdgcn_mfma_f32_16x16x32_bf16(al[mi], bh[ni], t, 0, 0, 0);
        t = __builtin_amdgcn_mfma_f32_16x16x32_bf16(ah[mi], bl[ni], t, 0, 0, 0);
        t = __builtin_amdgcn_mfma_f32_16x16x32_bf16(ah[mi], bh[ni], t, 0, 0, 0);
        acc[mi][ni] = t;
      }
  };

  do_stage(vnp, 64, Vn, 0, 1.f);
  do_stage(vnp, 64, Vn, 32, 1.f);
  #pragma unroll
  for (int mi=0;mi<4;mi++)
    #pragma unroll
    for (int ni=0;ni<4;ni++)
      #pragma unroll
      for (int r=0;r<4;r++)
        acc[mi][ni][r] = 2.f * tanh_f(acc[mi][ni][r]);
  for (int ks=0; ks<32; ks++) do_stage(ev, 1024, Ve, ks*32, 1.f);
  for (int ks=0; ks<16; ks++) do_stage(vcp, 512, Vc, ks*32, 2.f);

  #pragma unroll
  for (int mi=0;mi<4;mi++)
    #pragma unroll
    for (int ni=0;ni<4;ni++){
      int col = n0 + wc*64 + ni*16 + fr;
      #pragma unroll
      for (int r=0;r<4;r++){
        int row = m0 + wr*64 + mi*16 + (lane>>4)*4 + r;
        unsigned short hi, lo;
        splitbf(acc[mi][ni][r], hi, lo);
        xhi[row*EMB_ + col] = hi;
        xlo[row*EMB_ + col] = lo;
      }
    }
}

// ---------------------------------------------------------------------------
// Kernel 2: xW = x@Wx + bias -> bf16, column-permuted layout.
// Pre-split bf16 inputs -> staging is pure 16B load + 16B ds_write.
// ---------------------------------------------------------------------------
__global__ __launch_bounds__(256) void k_xw(
    const unsigned short* __restrict__ xhi, const unsigned short* __restrict__ xlo,
    const unsigned short* __restrict__ wThi, const unsigned short* __restrict__ wTlo,
    const float* __restrict__ bias, unsigned short* __restrict__ xwp)
{
  __shared__ unsigned short a_hi[128][40], a_lo[128][40];
  __shared__ unsigned short b_hi[128][40], b_lo[128][40];
  const int tid  = threadIdx.x;
  const int lane = tid & 63;
  const int w    = tid >> 6;
  const int wr = w >> 1, wc = w & 1;
  const int xcd = blockIdx.x & 7;
  const int xi  = blockIdx.x >> 3;
  const int mt = xcd*32 + (xi >> 5);
  const int nt = xi & 31;
  const int m0 = mt * 128, p0 = nt * 128;
  const int fr = lane & 15;
  const int fk = (lane >> 4) * 8;

  floatx4 acc[4][4];
  #pragma unroll
  for (int i=0;i<4;i++)
    #pragma unroll
    for (int j=0;j<4;j++)
      acc[i][j] = (floatx4){0.f,0.f,0.f,0.f};

  for (int ks=0; ks<16; ks++){
    const int kBase = ks*32;
    __syncthreads();
    #pragma unroll
    for (int c=0;c<2;c++){
      int ch = c*256 + tid;             // 0..511
      int r  = ch >> 2;                 // tile row / p-row
      int kk = (ch & 3)*8;              // k sub-chunk
      *(short8*)&a_hi[r][kk] = *(const short8*)(xhi  + (m0+r)*EMB_ + kBase + kk);
      *(short8*)&a_lo[r][kk] = *(const short8*)(xlo  + (m0+r)*EMB_ + kBase + kk);
      *(short8*)&b_hi[r][kk] = *(const short8*)(wThi + (p0+r)*EMB_ + kBase + kk);
      *(short8*)&b_lo[r][kk] = *(const short8*)(wTlo + (p0+r)*EMB_ + kBase + kk);
    }
    __syncthreads();
    short8 ah[4], al[4], bh[4], bl[4];
    #pragma unroll
    for (int mi=0;mi<4;mi++){
      ah[mi] = *(const short8*)&a_hi[wr*64 + mi*16 + fr][fk];
      al[mi] = *(const short8*)&a_lo[wr*64 + mi*16 + fr][fk];
    }
    #pragma unroll
    for (int ni=0;ni<4;ni++){
      bh[ni] = *(const short8*)&b_hi[wc*64 + ni*16 + fr][fk];
      bl[ni] = *(const short8*)&b_lo[wc*64 + ni*16 + fr][fk];
    }
    #pragma unroll
    for (int mi=0;mi<4;mi++)
      #pragma unroll
      for (int ni=0;ni<4;ni++){
        floatx4 t = acc[mi][ni];
        t = __builtin_amdgcn_mfma_f32_16x16x32_bf16(al[mi], bh[ni], t, 0, 0, 0);
        t = __builtin_amdgcn_mfma_f32_16x16x32_bf16(ah[mi], bl[ni], t, 0, 0, 0);
        t = __builtin_amdgcn_mfma_f32_16x16x32_bf16(ah[mi], bh[ni], t, 0, 0, 0);
        acc[mi][ni] = t;
      }
  }

  #pragma unroll
  for (int ni=0;ni<4;ni++){
    int p = p0 + wc*64 + ni*16 + fr;
    int n = ((p>>2)&3)*HS_ + (p>>4)*4 + (p&3);
    float bv = bias[n];
    #pragma unroll
    for (int mi=0;mi<4;mi++){
      #pragma unroll
      for (int r=0;r<4;r++){
        int row = m0 + wr*64 + mi*16 + (lane>>4)*4 + r;
        xwp[row*G4_ + p] = f2bf(acc[mi][ni][r] + bv);
      }
    }
  }
}

// ---------------------------------------------------------------------------
// Kernel 3: persistent cooperative LSTM scan.
// NEW geometry: 128 blocks x 512 threads (8 waves) = 4 groups x 32 col-blocks.
// Each block: 16 batch rows x 128 permuted gate-cols (32 h-cols); Wh fully in
// registers (16 gate-cols per wave). Halves barrier fan-in (32 arrive flags),
// go-pollers (32), and h-broadcast readers (32 x 32KB) vs round 2.
//  - hbuf: per-block contiguous 1KB tiles [grp][cb][16r][32c] bf16
//  - group h staged once into LDS per step (swizzle cc ^ ((rr>>1)&3), both
//    write and read conflict-free)
//  - go word replicated 8x; 4 pollers per replica
// ---------------------------------------------------------------------------
__global__ __launch_bounds__(512, 2) void k_lstm(
    const unsigned short* __restrict__ xwp, unsigned short* __restrict__ hbuf,
    int* __restrict__ flags, const unsigned short* __restrict__ whf,
    const float* __restrict__ Wc,
    const float* __restrict__ Wlin, const float* __restrict__ blin,
    float* __restrict__ out)
{
  __shared__ __align__(16) char hlds[32768];     // 32 tiles x 1024 B, swizzled
  __shared__ float xw_lds[16][132];
  __shared__ float gbuf[16][132];
  __shared__ unsigned short hstage[512];         // 16 rows x 32 h-cols
  __shared__ float red[512];
  const int tid  = threadIdx.x;
  const int lane = tid & 63;
  const int w    = tid >> 6;                     // 0..7
  const int phys = blockIdx.x;                   // 0..127
  const int grp  = (phys >> 3) & 3;              // batch group (4 blocks/XCD)
  const int cb   = (phys & 7)*4 + (phys >> 5);   // col-block 0..31 (XCD-major)
  const int r0   = grp * 16;                     // first batch row
  const int p0   = cb * 128;                     // first permuted gate-col
  int* const arrive = flags + (grp*32 + cb)*16;            // arrive word
  int* const gorep  = flags + 4096 + (grp*8 + (cb&7))*32;  // this block's go replica

  // Wh B-fragments: pre-packed layout, 32 coalesced 16B loads per wave.
  short8 wfrag[32];
  {
    const unsigned short* wbase = whf + ((size_t)(cb*8 + w))*16384 + lane*8;
    #pragma unroll
    for (int ks=0; ks<32; ks++)
      wfrag[ks] = *(const short8*)(wbase + ks*512);
  }

  // Elementwise assignment: thread -> (local row, local h-col), 1 element
  const int erow = tid >> 5, ej = tid & 31;
  const int hcol = cb*32 + ej;
  const float wc0 = Wc[hcol], wc1 = Wc[HS_ + hcol], wc2 = Wc[2*HS_ + hcol];
  const int gidx = (ej >> 2)*16 + (ej & 3);      // gate-0 index into 128-wide row
  float c_reg = 0.f;

  // A-fragment LDS read offset within tile ks:
  //  row = lane&15 (64B rows), chunk = lane>>4, swizzle chunk ^= (row>>1)&3
  const int hrow  = lane & 15;
  const int rdoff = hrow*64 + (((lane>>4) ^ ((hrow>>1)&3))*16);

  // xwp prefetch mapping: thread -> (row, 4-col chunk of 128)
  const int prow = tid >> 5, pchunk = tid & 31;
  const unsigned short* xwbase = xwp + ((size_t)(r0 + prow)*S_)*G4_ + p0 + pchunk*4;

  // Prefetch step-0 xw chunk into registers
  ushort4 xwpre = *(const ushort4*)(xwbase);

  for (int t=0; t<S_; t++){
    const unsigned short* hin  = hbuf + (t & 1)*B_*HS_ + grp*16384;           // group tiles
    unsigned short*       hout = hbuf + ((t+1) & 1)*B_*HS_ + (grp*32+cb)*512; // own tile

    // Commit prefetched xw chunk to LDS
    xw_lds[prow][pchunk*4+0] = bf2f(xwpre.x);
    xw_lds[prow][pchunk*4+1] = bf2f(xwpre.y);
    xw_lds[prow][pchunk*4+2] = bf2f(xwpre.z);
    xw_lds[prow][pchunk*4+3] = bf2f(xwpre.w);

    // Stage group h (32 KB contiguous) -> LDS, coalesced 16B chunks, swizzled
    #pragma unroll
    for (int it=0; it<4; it++){
      int cid = it*512 + tid;                 // 16B-chunk id, 0..2047
      short8 v = *(const short8*)(hin + cid*8);
      int t2 = cid >> 6;                      // tile 0..31
      int c  = cid & 63;                      // chunk in tile
      int rr = c >> 2, cc = c & 3;
      *(short8*)(hlds + t2*1024 + rr*64 + ((cc ^ ((rr>>1)&3))*16)) = v;
    }
    __syncthreads();

    // h @ Wh_slice : [16x1024]@[1024x16] per wave, A-fragments from LDS
    floatx4 a0 = (floatx4){0.f,0.f,0.f,0.f}, a1 = a0, a2 = a0, a3 = a0;
    #pragma unroll
    for (int ks=0; ks<32; ks+=4){
      short8 f0 = *(const short8*)(hlds + (ks+0)*1024 + rdoff);
      short8 f1 = *(const short8*)(hlds + (ks+1)*1024 + rdoff);
      short8 f2 = *(const short8*)(hlds + (ks+2)*1024 + rdoff);
      short8 f3 = *(const short8*)(hlds + (ks+3)*1024 + rdoff);
      a0 = __builtin_amdgcn_mfma_f32_16x16x32_bf16(f0, wfrag[ks+0], a0, 0,0,0);
      a1 = __builtin_amdgcn_mfma_f32_16x16x32_bf16(f1, wfrag[ks+1], a1, 0,0,0);
      a2 = __builtin_amdgcn_mfma_f32_16x16x32_bf16(f2, wfrag[ks+2], a2, 0,0,0);
      a3 = __builtin_amdgcn_mfma_f32_16x16x32_bf16(f3, wfrag[ks+3], a3, 0,0,0);
    }
    floatx4 acc = a0 + a1 + a2 + a3;

    // Scatter C to LDS: local col = w*16 + (lane&15), local row=(lane>>4)*4+r
    {
      const int gr = (lane>>4)*4;
      const int gc = w*16 + (lane & 15);
      gbuf[gr+0][gc] = acc[0];
      gbuf[gr+1][gc] = acc[1];
      gbuf[gr+2][gc] = acc[2];
      gbuf[gr+3][gc] = acc[3];
    }
    __syncthreads();

    // Elementwise LSTM cell (fp32 state in registers; peephole uses OLD c)
    {
      float gi = gbuf[erow][gidx     ] + xw_lds[erow][gidx     ];
      float gf = gbuf[erow][gidx +  4] + xw_lds[erow][gidx +  4];
      float gg = gbuf[erow][gidx +  8] + xw_lds[erow][gidx +  8];
      float go = gbuf[erow][gidx + 12] + xw_lds[erow][gidx + 12];
      float iv = sigm_f(gi + c_reg*wc0);
      float fv = sigm_f(gf + c_reg*wc1);
      float gv = tanh_f(gg);
      float ov = sigm_f(go + c_reg*wc2);
      float cn = fv*c_reg + iv*gv;
      float hn = ov*tanh_f(cn);
      c_reg = cn;
      hstage[tid] = f2bf(hn);                // flat = erow*32 + ej = tid
    }
    __syncthreads();

    // Wave 0: contiguous 1KB tile store (8 full lines), 2 x 8B per lane
    if (w == 0){
      const unsigned long long* hsrc = (const unsigned long long*)hstage;
      unsigned long long v0 = hsrc[lane*2], v1 = hsrc[lane*2+1];
      __hip_atomic_store((unsigned long long*)hout + lane*2,
                         v0, __ATOMIC_RELAXED, __HIP_MEMORY_SCOPE_AGENT);
      __hip_atomic_store((unsigned long long*)hout + lane*2+1,
                         v1, __ATOMIC_RELAXED, __HIP_MEMORY_SCOPE_AGENT);
      __builtin_amdgcn_s_waitcnt(0);             // h stores acked at coherence point
      if (lane == 0)
        __hip_atomic_store(arrive, t+1, __ATOMIC_RELAXED, __HIP_MEMORY_SCOPE_AGENT);
    }

    // Prefetch next step's xw chunk AFTER arrive-store (overlaps the go-wait)
    if (t+1 < S_) xwpre = *(const ushort4*)(xwbase + (size_t)(t+1)*G4_);

    // Leader (cb==0) wave 0: aggregate 32 arrive flags -> publish 8 go replicas.
    if (cb == 0 && w == 0){
      const int* fp = flags + (grp*32 + (lane & 31))*16;
      for (;;){
        int v = __hip_atomic_load(fp, __ATOMIC_RELAXED, __HIP_MEMORY_SCOPE_AGENT);
        if (__all(v >= t+1)) break;
        __builtin_amdgcn_s_sleep(2);
      }
      if (lane < 8)
        __hip_atomic_store(flags + 4096 + (grp*8 + lane)*32,
                           t+1, __ATOMIC_RELAXED, __HIP_MEMORY_SCOPE_AGENT);
    }
    // Everyone: single thread polls its go replica (4 pollers/replica line).
    if (tid == 0){
      for (;;){
        int v = __hip_atomic_load(gorep, __ATOMIC_RELAXED, __HIP_MEMORY_SCOPE_AGENT);
        if (v >= t+1) break;
        __builtin_amdgcn_s_sleep(2);
      }
    }
    __syncthreads();
    __builtin_amdgcn_fence(__ATOMIC_ACQUIRE, "agent");  // fresh h via coherence point
  }

  // Final: one (row, 64-col half) per block: out[r0+lr][ch*64 + cl]
  // h element (lr, k) lives at hbuf[grp*16384 + (k>>5)*512 + lr*32 + (k&31)]
  {
    const int lr  = cb & 15;
    const int ch  = cb >> 4;                // 0..1
    const int cl = tid & 63, kc = tid >> 6; // kc 0..7
    const int col = ch*64 + cl;
    const unsigned short* hg = hbuf + grp*16384;      // parity 0 after 512 steps
    float s = 0.f;
    for (int k = kc*128; k < kc*128 + 128; k++)
      s += bf2f(hg[(k>>5)*512 + lr*32 + (k&31)]) * Wlin[k*DIM_ + col];
    red[tid] = s;
    __syncthreads();
    if (tid < 64){
      float tot = blin[ch*64 + tid];
      #pragma unroll
      for (int q=0;q<8;q++) tot += red[q*64 + tid];
      out[(r0 + lr)*DIM_ + ch*64 + tid] = tot;
    }
  }
}

// ---------------------------------------------------------------------------
extern "C" void kernel_launch(void* const* d_in, const int* in_sizes, int n_in,
                              void* d_out, int out_size, void* d_ws, size_t ws_size,
                              hipStream_t stream)
{
  (void)in_sizes; (void)n_in; (void)out_size; (void)ws_size;
  const float* ev   = (const float*)d_in[0];
  const float* vcp  = (const float*)d_in[1];
  const float* vnp  = (const float*)d_in[2];
  const float* Ve   = (const float*)d_in[3];
  const float* Vc   = (const float*)d_in[4];
  const float* Vn   = (const float*)d_in[5];
  const float* Wx   = (const float*)d_in[6];
  const float* Wh   = (const float*)d_in[7];
  const float* Wc   = (const float*)d_in[8];
  const float* bias = (const float*)d_in[9];
  const float* Wl   = (const float*)d_in[10];
  const float* bl   = (const float*)d_in[11];
  float* outp = (float*)d_out;

  // ws layout (bytes):
  //   xhi  32MB @ 0         | xlo 32MB @ 32MB
  //   wThi  4MB @ 64MB      | wTlo 4MB @ 68MB
  //   whf   8MB @ 72MB
  //   xwp 256MB @ 80MB
  //   hbuf 256KB @ 336MB    | flags 32KB after
  char* ws = (char*)d_ws;
  unsigned short* xhi  = (unsigned short*)(ws);
  unsigned short* xlo  = (unsigned short*)(ws + (size_t)33554432);
  unsigned short* wThi = (unsigned short*)(ws + (size_t)67108864);
  unsigned short* wTlo = (unsigned short*)(ws + (size_t)71303168);
  unsigned short* whf  = (unsigned short*)(ws + (size_t)75497472);
  unsigned short* xwp  = (unsigned short*)(ws + (size_t)83886080);
  unsigned short* hbuf = (unsigned short*)(ws + (size_t)352321536);
  int* flags           = (int*)(ws + (size_t)352321536 + (size_t)262144);

  // h0 = 0, arrive flags = 0, go replicas = 0
  hipMemsetAsync(hbuf, 0, 262144 + 32768, stream);

  k_prep <<<dim3(24576), dim3(256), 0, stream>>>(Wx, Wh, wThi, wTlo, whf);
  k_embed<<<dim3(1024),  dim3(256), 0, stream>>>(ev, vcp, vnp, Ve, Vc, Vn, xhi, xlo);
  k_xw   <<<dim3(8192),  dim3(256), 0, stream>>>(xhi, xlo, wThi, wTlo, bias, xwp);

  const unsigned short* a0 = xwp;
  unsigned short* a1 = hbuf;
  int* a2 = flags;
  const unsigned short* a3 = whf;
  const float* a4 = Wc;
  const float* a5 = Wl; const float* a6 = bl;
  float* a7 = outp;
  void* args[] = {&a0, &a1, &a2, &a3, &a4, &a5, &a6, &a7};
  hipLaunchCooperativeKernel((void*)k_lstm, dim3(128), dim3(512), args, 0, stream);
}

// Round 4
// 3081.640 us; speedup vs baseline: 2.1616x; 1.7247x over previous
//
#include <hip/hip_runtime.h>

// Problem dims
#define HS_   1024
#define G4_   4096
#define EMB_  512
#define B_    64
#define S_    512
#define DIM_  128

typedef __attribute__((ext_vector_type(8))) short short8;
typedef __attribute__((ext_vector_type(4))) float floatx4;

__device__ __forceinline__ unsigned short f2bf(float f){
  union { float f; unsigned u; } v; v.f = f;
  unsigned r = v.u + 0x7FFFu + ((v.u >> 16) & 1u);   // RNE
  return (unsigned short)(r >> 16);
}
__device__ __forceinline__ float bf2f(unsigned short b){
  union { unsigned u; float f; } v; v.u = ((unsigned)b) << 16; return v.f;
}
// hi/lo split: f = bf2f(hi) + bf2f(lo) + O(f * 2^-18)
__device__ __forceinline__ void splitbf(float f, unsigned short& hi, unsigned short& lo){
  unsigned short h = f2bf(f);
  hi = h;
  lo = f2bf(f - bf2f(h));
}
__device__ __forceinline__ float sigm_f(float x){ return 1.0f/(1.0f + __expf(-x)); }
__device__ __forceinline__ float tanh_f(float x){ return 1.0f - 2.0f/(1.0f + __expf(2.0f*x)); }

// ---------------------------------------------------------------------------
// Kernel 0: weight prep.
//  - Wx -> transposed, column-permuted split-bf16 planes wT[p][k]
//  - Wh -> bf16 fragments in the exact k_lstm per-(cb,wave) register layout
//    (cb 0..31 x wv 0..7)
// ---------------------------------------------------------------------------
__global__ __launch_bounds__(256) void k_prep(
    const float* __restrict__ Wx, const float* __restrict__ Wh,
    unsigned short* __restrict__ wThi, unsigned short* __restrict__ wTlo,
    unsigned short* __restrict__ whf)
{
  const int id = blockIdx.x * 256 + threadIdx.x;
  if (blockIdx.x < 8192){                 // Wx part: 2M elems, id = p*512 + k
    const int p = id >> 9;
    const int k = id & 511;
    const int n = ((p>>2)&3)*HS_ + (p>>4)*4 + (p&3);
    unsigned short hi, lo;
    splitbf(Wx[k*G4_ + n], hi, lo);
    wThi[id] = hi;
    wTlo[id] = lo;
  } else {                                // Wh part: 4M elems
    const int f    = id - 2*1024*1024;
    const int j    = f & 7;
    const int lane = (f >> 3) & 63;
    const int ks   = (f >> 9) & 31;
    const int wv   = (f >> 14) & 7;
    const int cb   = f >> 17;             // 0..31
    const int p    = cb*128 + wv*16 + (lane & 15);
    const int gcol = ((p>>2)&3)*HS_ + (p>>4)*4 + (p&3);
    const int krow = ks*32 + (lane >> 4)*8 + j;
    whf[f] = f2bf(Wh[krow*G4_ + gcol]);
  }
}

// ---------------------------------------------------------------------------
// Kernel 1: x = event@Ve + 2*vc@Vc + 2*tanh(vn@Vn) -> split bf16 planes
// 128x128 tiles, split-bf16 3-pass 16x16x32 MFMA (~fp32 accuracy).
// ---------------------------------------------------------------------------
__global__ __launch_bounds__(256) void k_embed(
    const float* __restrict__ ev, const float* __restrict__ vcp, const float* __restrict__ vnp,
    const float* __restrict__ Ve, const float* __restrict__ Vc, const float* __restrict__ Vn,
    unsigned short* __restrict__ xhi, unsigned short* __restrict__ xlo)
{
  __shared__ unsigned short a_hi[128][40], a_lo[128][40];
  __shared__ unsigned short b_hi[128][40], b_lo[128][40];   // transposed: [n][k]
  const int tid  = threadIdx.x;
  const int lane = tid & 63;
  const int w    = tid >> 6;
  const int wr = w >> 1, wc = w & 1;
  const int mt = blockIdx.x >> 2;
  const int nt = blockIdx.x & 3;
  const int m0 = mt * 128, n0 = nt * 128;
  const int fr = lane & 15;
  const int fk = (lane >> 4) * 8;

  floatx4 acc[4][4];
  #pragma unroll
  for (int i=0;i<4;i++)
    #pragma unroll
    for (int j=0;j<4;j++)
      acc[i][j] = (floatx4){0.f,0.f,0.f,0.f};

  auto do_stage = [&](const float* A, int lda, const float* Bm, int kBase, float bscale){
    __syncthreads();
    #pragma unroll
    for (int c=0;c<4;c++){
      int flat = tid*16 + c*4;
      int r = flat >> 5, kk = flat & 31;
      float4 v = *(const float4*)(A + (m0+r)*lda + kBase + kk);
      splitbf(v.x, a_hi[r][kk+0], a_lo[r][kk+0]);
      splitbf(v.y, a_hi[r][kk+1], a_lo[r][kk+1]);
      splitbf(v.z, a_hi[r][kk+2], a_lo[r][kk+2]);
      splitbf(v.w, a_hi[r][kk+3], a_lo[r][kk+3]);
    }
    #pragma unroll
    for (int c=0;c<4;c++){
      int flat = tid*16 + c*4;
      int k = flat >> 7, nn = flat & 127;
      float4 v = *(const float4*)(Bm + (kBase+k)*EMB_ + n0 + nn);
      splitbf(v.x * bscale, b_hi[nn+0][k], b_lo[nn+0][k]);
      splitbf(v.y * bscale, b_hi[nn+1][k], b_lo[nn+1][k]);
      splitbf(v.z * bscale, b_hi[nn+2][k], b_lo[nn+2][k]);
      splitbf(v.w * bscale, b_hi[nn+3][k], b_lo[nn+3][k]);
    }
    __syncthreads();
    short8 ah[4], al[4], bh[4], bl[4];
    #pragma unroll
    for (int mi=0;mi<4;mi++){
      ah[mi] = *(const short8*)&a_hi[wr*64 + mi*16 + fr][fk];
      al[mi] = *(const short8*)&a_lo[wr*64 + mi*16 + fr][fk];
    }
    #pragma unroll
    for (int ni=0;ni<4;ni++){
      bh[ni] = *(const short8*)&b_hi[wc*64 + ni*16 + fr][fk];
      bl[ni] = *(const short8*)&b_lo[wc*64 + ni*16 + fr][fk];
    }
    #pragma unroll
    for (int mi=0;mi<4;mi++)
      #pragma unroll
      for (int ni=0;ni<4;ni++){
        floatx4 t = acc[mi][ni];
        t = __builtin_amdgcn_mfma_f32_16x16x32_bf16(al[mi], bh[ni], t, 0, 0, 0);
        t = __builtin_amdgcn_mfma_f32_16x16x32_bf16(ah[mi], bl[ni], t, 0, 0, 0);
        t = __builtin_amdgcn_mfma_f32_16x16x32_bf16(ah[mi], bh[ni], t, 0, 0, 0);
        acc[mi][ni] = t;
      }
  };

  do_stage(vnp, 64, Vn, 0, 1.f);
  do_stage(vnp, 64, Vn, 32, 1.f);
  #pragma unroll
  for (int mi=0;mi<4;mi++)
    #pragma unroll
    for (int ni=0;ni<4;ni++)
      #pragma unroll
      for (int r=0;r<4;r++)
        acc[mi][ni][r] = 2.f * tanh_f(acc[mi][ni][r]);
  for (int ks=0; ks<32; ks++) do_stage(ev, 1024, Ve, ks*32, 1.f);
  for (int ks=0; ks<16; ks++) do_stage(vcp, 512, Vc, ks*32, 2.f);

  #pragma unroll
  for (int mi=0;mi<4;mi++)
    #pragma unroll
    for (int ni=0;ni<4;ni++){
      int col = n0 + wc*64 + ni*16 + fr;
      #pragma unroll
      for (int r=0;r<4;r++){
        int row = m0 + wr*64 + mi*16 + (lane>>4)*4 + r;
        unsigned short hi, lo;
        splitbf(acc[mi][ni][r], hi, lo);
        xhi[row*EMB_ + col] = hi;
        xlo[row*EMB_ + col] = lo;
      }
    }
}

// ---------------------------------------------------------------------------
// Kernel 2: xW = x@Wx + bias -> bf16, column-permuted layout.
// Pre-split bf16 inputs -> staging is pure 16B load + 16B ds_write.
// ---------------------------------------------------------------------------
__global__ __launch_bounds__(256) void k_xw(
    const unsigned short* __restrict__ xhi, const unsigned short* __restrict__ xlo,
    const unsigned short* __restrict__ wThi, const unsigned short* __restrict__ wTlo,
    const float* __restrict__ bias, unsigned short* __restrict__ xwp)
{
  __shared__ unsigned short a_hi[128][40], a_lo[128][40];
  __shared__ unsigned short b_hi[128][40], b_lo[128][40];
  const int tid  = threadIdx.x;
  const int lane = tid & 63;
  const int w    = tid >> 6;
  const int wr = w >> 1, wc = w & 1;
  const int xcd = blockIdx.x & 7;
  const int xi  = blockIdx.x >> 3;
  const int mt = xcd*32 + (xi >> 5);
  const int nt = xi & 31;
  const int m0 = mt * 128, p0 = nt * 128;
  const int fr = lane & 15;
  const int fk = (lane >> 4) * 8;

  floatx4 acc[4][4];
  #pragma unroll
  for (int i=0;i<4;i++)
    #pragma unroll
    for (int j=0;j<4;j++)
      acc[i][j] = (floatx4){0.f,0.f,0.f,0.f};

  for (int ks=0; ks<16; ks++){
    const int kBase = ks*32;
    __syncthreads();
    #pragma unroll
    for (int c=0;c<2;c++){
      int ch = c*256 + tid;             // 0..511
      int r  = ch >> 2;                 // tile row / p-row
      int kk = (ch & 3)*8;              // k sub-chunk
      *(short8*)&a_hi[r][kk] = *(const short8*)(xhi  + (m0+r)*EMB_ + kBase + kk);
      *(short8*)&a_lo[r][kk] = *(const short8*)(xlo  + (m0+r)*EMB_ + kBase + kk);
      *(short8*)&b_hi[r][kk] = *(const short8*)(wThi + (p0+r)*EMB_ + kBase + kk);
      *(short8*)&b_lo[r][kk] = *(const short8*)(wTlo + (p0+r)*EMB_ + kBase + kk);
    }
    __syncthreads();
    short8 ah[4], al[4], bh[4], bl[4];
    #pragma unroll
    for (int mi=0;mi<4;mi++){
      ah[mi] = *(const short8*)&a_hi[wr*64 + mi*16 + fr][fk];
      al[mi] = *(const short8*)&a_lo[wr*64 + mi*16 + fr][fk];
    }
    #pragma unroll
    for (int ni=0;ni<4;ni++){
      bh[ni] = *(const short8*)&b_hi[wc*64 + ni*16 + fr][fk];
      bl[ni] = *(const short8*)&b_lo[wc*64 + ni*16 + fr][fk];
    }
    #pragma unroll
    for (int mi=0;mi<4;mi++)
      #pragma unroll
      for (int ni=0;ni<4;ni++){
        floatx4 t = acc[mi][ni];
        t = __builtin_amdgcn_mfma_f32_16x16x32_bf16(al[mi], bh[ni], t, 0, 0, 0);
        t = __builtin_amdgcn_mfma_f32_16x16x32_bf16(ah[mi], bl[ni], t, 0, 0, 0);
        t = __builtin_amdgcn_mfma_f32_16x16x32_bf16(ah[mi], bh[ni], t, 0, 0, 0);
        acc[mi][ni] = t;
      }
  }

  #pragma unroll
  for (int ni=0;ni<4;ni++){
    int p = p0 + wc*64 + ni*16 + fr;
    int n = ((p>>2)&3)*HS_ + (p>>4)*4 + (p&3);
    float bv = bias[n];
    #pragma unroll
    for (int mi=0;mi<4;mi++){
      #pragma unroll
      for (int r=0;r<4;r++){
        int row = m0 + wr*64 + mi*16 + (lane>>4)*4 + r;
        xwp[row*G4_ + p] = f2bf(acc[mi][ni][r] + bv);
      }
    }
  }
}

// ---------------------------------------------------------------------------
// Kernel 3: persistent cooperative LSTM scan.
// 128 blocks x 512 threads = 4 groups x 32 col-blocks.
// NEW vs round 3: leader/go barrier REMOVED. Per-tile seqno flags; each
// staging wave directly polls the 4 flags of the tiles it stages, then loads
// them via agent-scope (MALL-coherent) 8B atomic loads -> no buffer_inv,
// no go-publish/go-detect hops, one fewer __syncthreads per step.
// Cell gates re-laid as [row][hcol][4gates] -> single float4 read, no 8-way
// LDS bank conflict.
// Ordering invariant: iteration t stages only after flags >= t; a producer
// writes parity (t+1)&1 only after its iter-t poll saw >= t, which implies
// every reader of that buffer (iter t-1 staging) already finished.
// ---------------------------------------------------------------------------
__global__ __launch_bounds__(512, 2) void k_lstm(
    const unsigned short* __restrict__ xwp, unsigned short* __restrict__ hbuf,
    int* __restrict__ flags, const unsigned short* __restrict__ whf,
    const float* __restrict__ Wc,
    const float* __restrict__ Wlin, const float* __restrict__ blin,
    float* __restrict__ out)
{
  __shared__ __align__(16) char hlds[32768];     // 32 tiles x 1024 B, swizzled
  __shared__ float xw2[16][132];                 // [row][hcol*4 + gate]
  __shared__ float gbuf2[16][132];               // [row][hcol*4 + gate]
  __shared__ __align__(16) unsigned short hstage[512];  // 16 rows x 32 h-cols
  __shared__ float red[512];
  const int tid  = threadIdx.x;
  const int lane = tid & 63;
  const int w    = tid >> 6;                     // 0..7
  const int phys = blockIdx.x;                   // 0..127
  const int grp  = (phys >> 3) & 3;              // batch group (4 blocks/XCD)
  const int cb   = (phys & 7)*4 + (phys >> 5);   // col-block 0..31 (XCD-major)
  const int r0   = grp * 16;                     // first batch row
  const int p0   = cb * 128;                     // first permuted gate-col
  int* const arrive = flags + (grp*32 + cb)*16;                 // own seqno
  const int* const pollp = flags + (grp*32 + w*4 + (lane&3))*16; // tiles 4w..4w+3

  // Wh B-fragments: pre-packed layout, 32 coalesced 16B loads per wave.
  short8 wfrag[32];
  {
    const unsigned short* wbase = whf + ((size_t)(cb*8 + w))*16384 + lane*8;
    #pragma unroll
    for (int ks=0; ks<32; ks++)
      wfrag[ks] = *(const short8*)(wbase + ks*512);
  }

  // Elementwise assignment: thread -> (local row erow, local h-col ej)
  const int erow = tid >> 5, ej = tid & 31;
  const int hcol = cb*32 + ej;
  const float wc0 = Wc[hcol], wc1 = Wc[HS_ + hcol], wc2 = Wc[2*HS_ + hcol];
  float c_reg = 0.f;

  // A-fragment LDS read offset within tile ks:
  //  row = lane&15 (64B rows), chunk = lane>>4, swizzle chunk ^= (row>>1)&3
  const int hrow  = lane & 15;
  const int rdoff = hrow*64 + (((lane>>4) ^ ((hrow>>1)&3))*16);

  // xwp prefetch mapping: thread (erow, ej) -> 4 permuted cols ej*4..ej*4+3
  const unsigned short* xwbase = xwp + ((size_t)(r0 + erow)*S_)*G4_ + p0 + ej*4;
  // xw2 commit base index: p_local = ej*4+q -> [erow][(ej>>2)*16 + q*4 + (ej&3)]
  const int xoff = (ej>>2)*16 + (ej&3);

  // Prefetch step-0 xw chunk into registers
  ushort4 xwpre = *(const ushort4*)(xwbase);

  for (int t=0; t<S_; t++){
    const unsigned short* hin  = hbuf + (t & 1)*B_*HS_ + grp*16384;           // group tiles
    unsigned short*       hout = hbuf + ((t+1) & 1)*B_*HS_ + (grp*32+cb)*512; // own tile

    // Commit prefetched xw chunk to LDS (prev cell reads are behind a barrier)
    xw2[erow][xoff     ] = bf2f(xwpre.x);
    xw2[erow][xoff +  4] = bf2f(xwpre.y);
    xw2[erow][xoff +  8] = bf2f(xwpre.z);
    xw2[erow][xoff + 12] = bf2f(xwpre.w);

    // Per-wave: poll own 4 tiles' seqnos >= t, then MALL-coherent load -> LDS
    {
      for (;;){
        int v = __hip_atomic_load(pollp, __ATOMIC_RELAXED, __HIP_MEMORY_SCOPE_AGENT);
        if (__all(v >= t)) break;
        __builtin_amdgcn_s_sleep(1);
      }
      asm volatile("" ::: "memory");
      #pragma unroll
      for (int it=0; it<4; it++){
        int cid = w*256 + it*64 + lane;         // 16B-chunk id within group
        const unsigned long long* src = (const unsigned long long*)(hin + cid*8);
        unsigned long long vlo = __hip_atomic_load(src+0, __ATOMIC_RELAXED, __HIP_MEMORY_SCOPE_AGENT);
        unsigned long long vhi = __hip_atomic_load(src+1, __ATOMIC_RELAXED, __HIP_MEMORY_SCOPE_AGENT);
        union { unsigned long long u[2]; short8 v; } cv;
        cv.u[0] = vlo; cv.u[1] = vhi;
        int t2 = cid >> 6;                      // tile 0..31
        int c  = cid & 63;                      // chunk in tile
        int rr = c >> 2, cc = c & 3;
        *(short8*)(hlds + t2*1024 + rr*64 + ((cc ^ ((rr>>1)&3))*16)) = cv.v;
      }
    }
    __syncthreads();

    // h @ Wh_slice : [16x1024]@[1024x16] per wave, A-fragments from LDS
    floatx4 a0 = (floatx4){0.f,0.f,0.f,0.f}, a1 = a0, a2 = a0, a3 = a0;
    #pragma unroll
    for (int ks=0; ks<32; ks+=4){
      short8 f0 = *(const short8*)(hlds + (ks+0)*1024 + rdoff);
      short8 f1 = *(const short8*)(hlds + (ks+1)*1024 + rdoff);
      short8 f2 = *(const short8*)(hlds + (ks+2)*1024 + rdoff);
      short8 f3 = *(const short8*)(hlds + (ks+3)*1024 + rdoff);
      a0 = __builtin_amdgcn_mfma_f32_16x16x32_bf16(f0, wfrag[ks+0], a0, 0,0,0);
      a1 = __builtin_amdgcn_mfma_f32_16x16x32_bf16(f1, wfrag[ks+1], a1, 0,0,0);
      a2 = __builtin_amdgcn_mfma_f32_16x16x32_bf16(f2, wfrag[ks+2], a2, 0,0,0);
      a3 = __builtin_amdgcn_mfma_f32_16x16x32_bf16(f3, wfrag[ks+3], a3, 0,0,0);
    }
    floatx4 acc = a0 + a1 + a2 + a3;

    // Scatter C: p_local = w*16+(lane&15) -> [row][(w*4+(lane&3))*4 + ((lane>>2)&3)]
    {
      const int gr  = (lane>>4)*4;
      const int gi0 = w*16 + (lane&3)*4 + ((lane>>2)&3);
      gbuf2[gr+0][gi0] = acc[0];
      gbuf2[gr+1][gi0] = acc[1];
      gbuf2[gr+2][gi0] = acc[2];
      gbuf2[gr+3][gi0] = acc[3];
    }
    __syncthreads();

    // Elementwise LSTM cell: one float4 per operand, conflict-free
    {
      float4 gv = *(const float4*)&gbuf2[erow][ej*4];
      float4 xv = *(const float4*)&xw2[erow][ej*4];
      float iv = sigm_f(gv.x + xv.x + c_reg*wc0);
      float fv = sigm_f(gv.y + xv.y + c_reg*wc1);
      float gg = tanh_f(gv.z + xv.z);
      float ov = sigm_f(gv.w + xv.w + c_reg*wc2);
      float cn = fv*c_reg + iv*gg;
      float hn = ov*tanh_f(cn);
      c_reg = cn;
      hstage[tid] = f2bf(hn);                // flat = erow*32 + ej = tid
    }
    __syncthreads();

    // Wave 0: contiguous 1KB tile store (8 full lines), then seqno publish
    if (w == 0){
      const unsigned long long* hsrc = (const unsigned long long*)hstage;
      unsigned long long v0 = hsrc[lane*2], v1 = hsrc[lane*2+1];
      __hip_atomic_store((unsigned long long*)hout + lane*2,
                         v0, __ATOMIC_RELAXED, __HIP_MEMORY_SCOPE_AGENT);
      __hip_atomic_store((unsigned long long*)hout + lane*2+1,
                         v1, __ATOMIC_RELAXED, __HIP_MEMORY_SCOPE_AGENT);
      __builtin_amdgcn_s_waitcnt(0);             // h stores acked at coherence point
      if (lane == 0)
        __hip_atomic_store(arrive, t+1, __ATOMIC_RELAXED, __HIP_MEMORY_SCOPE_AGENT);
    }

    // Prefetch next step's xw chunk (overlaps next poll / other blocks' work)
    if (t+1 < S_) xwpre = *(const ushort4*)(xwbase + (size_t)(t+1)*G4_);
  }

  // Final visibility: confirm all tiles at seq 512, then invalidate caches so
  // the normal loads below refill fresh from the coherence point.
  {
    for (;;){
      int v = __hip_atomic_load(pollp, __ATOMIC_RELAXED, __HIP_MEMORY_SCOPE_AGENT);
      if (__all(v >= S_)) break;
      __builtin_amdgcn_s_sleep(1);
    }
    __builtin_amdgcn_fence(__ATOMIC_ACQUIRE, "agent");
  }
  __syncthreads();

  // Final: one (row, 64-col half) per block: out[r0+lr][ch*64 + cl]
  // h element (lr, k) lives at hbuf[grp*16384 + (k>>5)*512 + lr*32 + (k&31)]
  {
    const int lr  = cb & 15;
    const int ch  = cb >> 4;                // 0..1
    const int cl = tid & 63, kc = tid >> 6; // kc 0..7
    const int col = ch*64 + cl;
    const unsigned short* hg = hbuf + grp*16384;      // parity 0 after 512 steps
    float s = 0.f;
    for (int k = kc*128; k < kc*128 + 128; k++)
      s += bf2f(hg[(k>>5)*512 + lr*32 + (k&31)]) * Wlin[k*DIM_ + col];
    red[tid] = s;
    __syncthreads();
    if (tid < 64){
      float tot = blin[ch*64 + tid];
      #pragma unroll
      for (int q=0;q<8;q++) tot += red[q*64 + tid];
      out[(r0 + lr)*DIM_ + ch*64 + tid] = tot;
    }
  }
}

// ---------------------------------------------------------------------------
extern "C" void kernel_launch(void* const* d_in, const int* in_sizes, int n_in,
                              void* d_out, int out_size, void* d_ws, size_t ws_size,
                              hipStream_t stream)
{
  (void)in_sizes; (void)n_in; (void)out_size; (void)ws_size;
  const float* ev   = (const float*)d_in[0];
  const float* vcp  = (const float*)d_in[1];
  const float* vnp  = (const float*)d_in[2];
  const float* Ve   = (const float*)d_in[3];
  const float* Vc   = (const float*)d_in[4];
  const float* Vn   = (const float*)d_in[5];
  const float* Wx   = (const float*)d_in[6];
  const float* Wh   = (const float*)d_in[7];
  const float* Wc   = (const float*)d_in[8];
  const float* bias = (const float*)d_in[9];
  const float* Wl   = (const float*)d_in[10];
  const float* bl   = (const float*)d_in[11];
  float* outp = (float*)d_out;

  // ws layout (bytes):
  //   xhi  32MB @ 0         | xlo 32MB @ 32MB
  //   wThi  4MB @ 64MB      | wTlo 4MB @ 68MB
  //   whf   8MB @ 72MB
  //   xwp 256MB @ 80MB
  //   hbuf 256KB @ 336MB    | flags 32KB after
  char* ws = (char*)d_ws;
  unsigned short* xhi  = (unsigned short*)(ws);
  unsigned short* xlo  = (unsigned short*)(ws + (size_t)33554432);
  unsigned short* wThi = (unsigned short*)(ws + (size_t)67108864);
  unsigned short* wTlo = (unsigned short*)(ws + (size_t)71303168);
  unsigned short* whf  = (unsigned short*)(ws + (size_t)75497472);
  unsigned short* xwp  = (unsigned short*)(ws + (size_t)83886080);
  unsigned short* hbuf = (unsigned short*)(ws + (size_t)352321536);
  int* flags           = (int*)(ws + (size_t)352321536 + (size_t)262144);

  // h0 = 0, per-tile seqnos = 0
  hipMemsetAsync(hbuf, 0, 262144 + 32768, stream);

  k_prep <<<dim3(24576), dim3(256), 0, stream>>>(Wx, Wh, wThi, wTlo, whf);
  k_embed<<<dim3(1024),  dim3(256), 0, stream>>>(ev, vcp, vnp, Ve, Vc, Vn, xhi, xlo);
  k_xw   <<<dim3(8192),  dim3(256), 0, stream>>>(xhi, xlo, wThi, wTlo, bias, xwp);

  const unsigned short* a0 = xwp;
  unsigned short* a1 = hbuf;
  int* a2 = flags;
  const unsigned short* a3 = whf;
  const float* a4 = Wc;
  const float* a5 = Wl; const float* a6 = bl;
  float* a7 = outp;
  void* args[] = {&a0, &a1, &a2, &a3, &a4, &a5, &a6, &a7};
  hipLaunchCooperativeKernel((void*)k_lstm, dim3(128), dim3(512), args, 0, stream);
}